// Round 10
// baseline (81.537 us; speedup 1.0000x reference)
//
#include <hip/hip_runtime.h>
#include <math.h>

typedef unsigned long long u64;
typedef __attribute__((ext_vector_type(8))) short bf16x8;
typedef __attribute__((ext_vector_type(4))) float f32x4;

#define S_DIM 1023
#define B_DIM 64
#define I_DIM 1024
#define CTX_DIM 784
#define CTX4 196          // CTX_DIM / 4
#define NWROWS 16         // 2^M buckets
#define NTASK (S_DIM * NWROWS)

#define LR_C 0.01f
#define WC_C 5.0f
#define LO_C (-6.906754778648554f)
#define HI_C ( 6.906754778648554f)

__device__ __forceinline__ float dot4(float4 a, float4 b) {
    return a.x * b.x + a.y * b.y + a.z * b.z + a.w * b.w;
}

__device__ __forceinline__ float4 upd4(float4 w, float4 a, float c) {
    float4 r;
    r.x = fminf(fmaxf(w.x - c * a.x, -WC_C), WC_C);
    r.y = fminf(fmaxf(w.y - c * a.y, -WC_C), WC_C);
    r.z = fminf(fmaxf(w.z - c * a.z, -WC_C), WC_C);
    r.w = fminf(fmaxf(w.w - c * a.w, -WC_C), WC_C);
    return r;
}

__device__ __forceinline__ short f2bf(float f) {
    union { float f; unsigned u; } cv; cv.f = f;
    unsigned r = cv.u + 0x7fffu + ((cv.u >> 16) & 1u);   // RNE
    return (short)(r >> 16);
}

// ---------------- kernel A: context -> float4-transposed layout + bias row ----------------
__global__ __launch_bounds__(256) void prep_kernel(
    const float* __restrict__ context,   // [B, CTX]
    const float* __restrict__ bias,      // [1]
    float4* __restrict__ ctxT4,          // [CTX4][B]
    float* __restrict__ out_logits)      // [B, S+1]
{
    int g = blockIdx.x * 256 + threadIdx.x;
    int k4 = g >> 6;
    int b  = g & 63;
    ctxT4[g] = *(const float4*)(context + (size_t)b * CTX_DIM + k4 * 4);
    if (g < B_DIM) out_logits[(size_t)g * (S_DIM + 1)] = bias[0];
}

// ---------------- kernel A2: pack logit into bf16 MFMA B-fragments ----------------
// layout: pack_b[nt(4)][kb(32)][lane(64)][j(8)] = bf16(logit[b = nt*16+(l&15)][i = kb*32+(l>>4)*8+j])
__global__ __launch_bounds__(256) void pack_kernel(
    const float* __restrict__ logit,     // [B, I]
    short* __restrict__ pack_b)          // [4*32*64*8]
{
    int g = blockIdx.x * 256 + threadIdx.x;     // 0..8191 = (nt*32+kb)*64 + l
    int l  = g & 63;
    int kb = (g >> 6) & 31;
    int nt = g >> 11;
    int b  = nt * 16 + (l & 15);
    int i0 = kb * 32 + (l >> 4) * 8;
    const float* src = logit + (size_t)b * I_DIM + i0;
    bf16x8 v;
    #pragma unroll
    for (int j = 0; j < 8; ++j) v[j] = f2bf(src[j]);
    *(bf16x8*)(pack_b + (size_t)g * 8) = v;
}

// ---------------- kernel B: halfspace hash -> membership masks ----------------
__global__ __launch_bounds__(256) void gln_idx_kernel(
    const float* __restrict__ cm,        // [S, 4, CTX]
    const float* __restrict__ cb,        // [S, 4]
    const float4* __restrict__ ctxT4,    // [CTX4][B]
    u64* __restrict__ mask_g)            // [S*16]
{
    __shared__ float red[4][4][64];      // [q][m][b]
    __shared__ int   bits[4][64];
    __shared__ float cb_lds[4];

    const int s = blockIdx.x;
    const int t = threadIdx.x;
    if (t < 4) cb_lds[t] = cb[s * 4 + t];

    const int b = t & 63;
    const int q = __builtin_amdgcn_readfirstlane(t >> 6);   // k-quarter, uniform
    const float4* cmr = (const float4*)(cm + (size_t)s * 4 * CTX_DIM);

    float a0 = 0.f, a1 = 0.f, a2 = 0.f, a3 = 0.f;
    const int k0 = q * 49;
    #pragma unroll 7
    for (int kk = 0; kk < 49; ++kk) {
        int k4 = k0 + kk;
        float4 c4 = ctxT4[k4 * 64 + b];
        a0 += dot4(cmr[k4], c4);
        a1 += dot4(cmr[CTX4 + k4], c4);
        a2 += dot4(cmr[2 * CTX4 + k4], c4);
        a3 += dot4(cmr[3 * CTX4 + k4], c4);
    }
    red[q][0][b] = a0;
    red[q][1][b] = a1;
    red[q][2][b] = a2;
    red[q][3][b] = a3;
    __syncthreads();

    {
        int m = t >> 6, bb = t & 63;
        float sum = red[0][m][bb] + red[1][m][bb] + red[2][m][bb] + red[3][m][bb];
        bits[m][bb] = (sum > cb_lds[m]) ? 1 : 0;
    }
    __syncthreads();

    if (t < B_DIM) {
        int v = bits[0][t] + 2 * bits[1][t] + 4 * bits[2][t] + 8 * bits[3][t];
        u64 my = 0;
        #pragma unroll
        for (int kk = 0; kk < NWROWS; ++kk) {
            u64 mk = __ballot(v == kk);
            if (t == kk) my = mk;
        }
        if (t < NWROWS) mask_g[s * NWROWS + t] = my;
    }
}

// ---------------- kernel C: block per s -- MFMA full P + streaming update ----------------
__global__ __launch_bounds__(256, 4) void gln_mfma_kernel(
    const float* __restrict__ logit,     // [B, I] fp32
    const float* __restrict__ target,    // [B]
    const float* __restrict__ weights,   // [S, 16, I] fp32
    const u64*   __restrict__ mask_g,    // [S*16]
    const short* __restrict__ pack_b,    // bf16 B-fragments
    float* __restrict__ out_logits,      // [B, S+1]
    float* __restrict__ new_weights)     // [S, 16, I]
{
    __shared__ u64   mask_lds[NWROWS];
    __shared__ int   lastb_lds[NWROWS];
    __shared__ float coef_lds[NWROWS];

    const int s  = blockIdx.x;
    const int t  = threadIdx.x;
    const int wv = t >> 6;
    const int l  = t & 63;

    if (t < NWROWS) {
        u64 m = mask_g[s * NWROWS + t];
        mask_lds[t]  = m;
        lastb_lds[t] = m ? (63 - __clzll(m)) : -1;
    }

    // ---- MFMA phase: P[16][64] = W[s](16x1024) . logit^T(1024x64); wave wv -> cols wv*16..+15
    // A-frag: lane l holds A[row=l&15][k=(l>>4)*8+j]; B-frag from pack_b; C: col=l&15, row=(l>>4)*4+j
    const float* Abase = weights + (size_t)s * (NWROWS * I_DIM)
                       + (size_t)(l & 15) * I_DIM + ((l >> 4) * 8);
    const bf16x8* Bbase = (const bf16x8*)pack_b + (size_t)wv * 32 * 64 + l;
    f32x4 acc = {0.f, 0.f, 0.f, 0.f};
    #pragma unroll 4
    for (int kb = 0; kb < 32; ++kb) {
        float4 x = *(const float4*)(Abase + kb * 32);
        float4 y = *(const float4*)(Abase + kb * 32 + 4);
        bf16x8 af;
        af[0] = f2bf(x.x); af[1] = f2bf(x.y); af[2] = f2bf(x.z); af[3] = f2bf(x.w);
        af[4] = f2bf(y.x); af[5] = f2bf(y.y); af[6] = f2bf(y.z); af[7] = f2bf(y.w);
        bf16x8 bfr = Bbase[(size_t)kb * 64];
        acc = __builtin_amdgcn_mfma_f32_16x16x32_bf16(af, bfr, acc, 0, 0, 0);
    }

    __syncthreads();    // mask_lds visible to all

    // ---- selection: out[b] = P[idx[b]][b]; coef for last-b of each row
    const int col = wv * 16 + (l & 15);
    #pragma unroll
    for (int j = 0; j < 4; ++j) {
        int row = (l >> 4) * 4 + j;
        u64 m = mask_lds[row];
        if ((m >> col) & 1) {
            float o = fminf(fmaxf(acc[j], LO_C), HI_C);
            out_logits[(size_t)col * (S_DIM + 1) + s + 1] = o;
            if (col == lastb_lds[row])
                coef_lds[row] = LR_C * (1.0f / (1.0f + expf(-o)) - target[col]);
        }
    }
    __syncthreads();    // coef_lds visible

    // ---- update phase: pure coalesced stream, 16 independent iterations
    const float4* W4 = (const float4*)(weights + (size_t)s * (NWROWS * I_DIM));
    float4*       D4 = (float4*)(new_weights + (size_t)s * (NWROWS * I_DIM));
    const float4* L4 = (const float4*)logit;
    #pragma unroll 8
    for (int r = 0; r < NWROWS; ++r) {
        const int lb = lastb_lds[r];
        float4 w = W4[r * 256 + t];
        float4 o;
        if (lb < 0) {
            o = w;
        } else {
            o = upd4(w, L4[lb * 256 + t], coef_lds[r]);
        }
        D4[r * 256 + t] = o;
    }
}

extern "C" void kernel_launch(void* const* d_in, const int* in_sizes, int n_in,
                              void* d_out, int out_size, void* d_ws, size_t ws_size,
                              hipStream_t stream) {
    const float* logit   = (const float*)d_in[0];   // [B, I, 1]
    const float* context = (const float*)d_in[1];   // [B, CTX]
    const float* target  = (const float*)d_in[2];   // [B, 1]
    const float* cm      = (const float*)d_in[3];   // [1, S, 4, CTX]
    const float* cb      = (const float*)d_in[4];   // [1, S, 4, 1]
    const float* weights = (const float*)d_in[5];   // [1, S, 16, I]
    const float* bias    = (const float*)d_in[6];   // [1]

    float* out_logits  = (float*)d_out;                       // [B, S+1]
    float* new_weights = out_logits + (size_t)B_DIM * (S_DIM + 1);

    char* ws = (char*)d_ws;
    float4* ctxT4  = (float4*)ws;    ws += (size_t)CTX4 * B_DIM * 16;   // 200704 B
    u64*    mask_g = (u64*)ws;       ws += (size_t)NTASK * 8;           // 130944 B
    short*  packb  = (short*)ws;                                        // 131072 B

    prep_kernel<<<CTX4 * B_DIM / 256, 256, 0, stream>>>(context, bias, ctxT4, out_logits);
    pack_kernel<<<32, 256, 0, stream>>>(logit, packb);
    gln_idx_kernel<<<S_DIM, 256, 0, stream>>>(cm, cb, ctxT4, mask_g);
    gln_mfma_kernel<<<S_DIM, 256, 0, stream>>>(logit, target, weights, mask_g, packb,
                                               out_logits, new_weights);
}

// Round 11
// 63.888 us; speedup vs baseline: 1.2762x; 1.2762x over previous
//
#include <hip/hip_runtime.h>
#include <math.h>

typedef unsigned long long u64;
typedef __attribute__((ext_vector_type(8))) short bf16x8;
typedef __attribute__((ext_vector_type(4))) float f32x4;

#define S_DIM 1023
#define B_DIM 64
#define I_DIM 1024
#define CTX_DIM 784
#define CTX4 196          // CTX_DIM / 4
#define NWROWS 16         // 2^M buckets
#define NTASK (S_DIM * NWROWS)

#define LR_C 0.01f
#define WC_C 5.0f
#define LO_C (-6.906754778648554f)
#define HI_C ( 6.906754778648554f)

__device__ __forceinline__ float dot4(float4 a, float4 b) {
    return a.x * b.x + a.y * b.y + a.z * b.z + a.w * b.w;
}

__device__ __forceinline__ float4 upd4(float4 w, float4 a, float c) {
    float4 r;
    r.x = fminf(fmaxf(w.x - c * a.x, -WC_C), WC_C);
    r.y = fminf(fmaxf(w.y - c * a.y, -WC_C), WC_C);
    r.z = fminf(fmaxf(w.z - c * a.z, -WC_C), WC_C);
    r.w = fminf(fmaxf(w.w - c * a.w, -WC_C), WC_C);
    return r;
}

__device__ __forceinline__ short f2bf(float f) {
    union { float f; unsigned u; } cv; cv.f = f;
    unsigned r = cv.u + 0x7fffu + ((cv.u >> 16) & 1u);   // RNE
    return (short)(r >> 16);
}

// ---------------- kernel A: context -> float4-transposed layout + bias row ----------------
__global__ __launch_bounds__(256) void prep_kernel(
    const float* __restrict__ context,   // [B, CTX]
    const float* __restrict__ bias,      // [1]
    float4* __restrict__ ctxT4,          // [CTX4][B]
    float* __restrict__ out_logits)      // [B, S+1]
{
    int g = blockIdx.x * 256 + threadIdx.x;
    int k4 = g >> 6;
    int b  = g & 63;
    ctxT4[g] = *(const float4*)(context + (size_t)b * CTX_DIM + k4 * 4);
    if (g < B_DIM) out_logits[(size_t)g * (S_DIM + 1)] = bias[0];
}

// ---------------- kernel A2: pack logit into bf16 MFMA B-fragments ----------------
// pack_b[nt][kb][lane][j] = bf16(logit[b = nt*16+(l&15)][i = kb*32+(l>>4)*8+j])
__global__ __launch_bounds__(256) void pack_kernel(
    const float* __restrict__ logit,     // [B, I]
    short* __restrict__ pack_b)          // [4*32*64*8]
{
    int g = blockIdx.x * 256 + threadIdx.x;     // (nt*32+kb)*64 + l
    int l  = g & 63;
    int kb = (g >> 6) & 31;
    int nt = g >> 11;
    int b  = nt * 16 + (l & 15);
    int i0 = kb * 32 + (l >> 4) * 8;
    const float* src = logit + (size_t)b * I_DIM + i0;
    bf16x8 v;
    #pragma unroll
    for (int j = 0; j < 8; ++j) v[j] = f2bf(src[j]);
    *(bf16x8*)(pack_b + (size_t)g * 8) = v;
}

// ---------------- kernel B: halfspace hash -> membership masks ----------------
__global__ __launch_bounds__(256) void gln_idx_kernel(
    const float* __restrict__ cm,        // [S, 4, CTX]
    const float* __restrict__ cb,        // [S, 4]
    const float4* __restrict__ ctxT4,    // [CTX4][B]
    u64* __restrict__ mask_g)            // [S*16]
{
    __shared__ float red[4][4][64];      // [q][m][b]
    __shared__ int   bits[4][64];
    __shared__ float cb_lds[4];

    const int s = blockIdx.x;
    const int t = threadIdx.x;
    if (t < 4) cb_lds[t] = cb[s * 4 + t];

    const int b = t & 63;
    const int q = __builtin_amdgcn_readfirstlane(t >> 6);   // k-quarter, uniform
    const float4* cmr = (const float4*)(cm + (size_t)s * 4 * CTX_DIM);

    float a0 = 0.f, a1 = 0.f, a2 = 0.f, a3 = 0.f;
    const int k0 = q * 49;
    #pragma unroll 7
    for (int kk = 0; kk < 49; ++kk) {
        int k4 = k0 + kk;
        float4 c4 = ctxT4[k4 * 64 + b];
        a0 += dot4(cmr[k4], c4);
        a1 += dot4(cmr[CTX4 + k4], c4);
        a2 += dot4(cmr[2 * CTX4 + k4], c4);
        a3 += dot4(cmr[3 * CTX4 + k4], c4);
    }
    red[q][0][b] = a0;
    red[q][1][b] = a1;
    red[q][2][b] = a2;
    red[q][3][b] = a3;
    __syncthreads();

    {
        int m = t >> 6, bb = t & 63;
        float sum = red[0][m][bb] + red[1][m][bb] + red[2][m][bb] + red[3][m][bb];
        bits[m][bb] = (sum > cb_lds[m]) ? 1 : 0;
    }
    __syncthreads();

    if (t < B_DIM) {
        int v = bits[0][t] + 2 * bits[1][t] + 4 * bits[2][t] + 8 * bits[3][t];
        u64 my = 0;
        #pragma unroll
        for (int kk = 0; kk < NWROWS; ++kk) {
            u64 mk = __ballot(v == kk);
            if (t == kk) my = mk;
        }
        if (t < NWROWS) mask_g[s * NWROWS + t] = my;
    }
}

// ---------------- kernel C: block per s -- LDS-staged bf16 MFMA + streaming update ----------------
// LDS A tile: bf16, 16B-slot index = row*128 + ((i>>3) ^ (row&7))  [XOR swizzle]
__global__ __launch_bounds__(256, 4) void gln_mfma2_kernel(
    const float* __restrict__ logit,     // [B, I] fp32
    const float* __restrict__ target,    // [B]
    const float* __restrict__ weights,   // [S, 16, I] fp32
    const u64*   __restrict__ mask_g,    // [S*16]
    const short* __restrict__ pack_b,    // bf16 B-fragments
    float* __restrict__ out_logits,      // [B, S+1]
    float* __restrict__ new_weights)     // [S, 16, I]
{
    __shared__ short Abf[NWROWS * I_DIM];   // 32 KB swizzled bf16 W[s]
    __shared__ u64   mask_lds[NWROWS];
    __shared__ int   lastb_lds[NWROWS];
    __shared__ float coef_lds[NWROWS];

    const int s  = blockIdx.x;
    const int t  = threadIdx.x;
    const int wv = t >> 6;
    const int l  = t & 63;

    if (t < NWROWS) {
        u64 m = mask_g[s * NWROWS + t];
        mask_lds[t]  = m;
        lastb_lds[t] = m ? (63 - __clzll(m)) : -1;
    }

    // ---- stage: coalesced fp32 read of W[s], cvt, swizzled bf16 LDS write ----
    const float4* W4 = (const float4*)(weights + (size_t)s * (NWROWS * I_DIM));
    #pragma unroll
    for (int j = 0; j < 16; ++j) {
        float4 w = W4[t + j * 256];              // row j, cols 4t..4t+3
        int slot = j * 128 + (((t >> 1)) ^ (j & 7));
        short4 v;
        v.x = f2bf(w.x); v.y = f2bf(w.y); v.z = f2bf(w.z); v.w = f2bf(w.w);
        *(short4*)(Abf + slot * 8 + (t & 1) * 4) = v;   // ds_write_b64
    }
    __syncthreads();

    // ---- MFMA: P[16][64] = W[s] . logit^T; wave wv -> cols wv*16..+15 ----
    const int row = l & 15;
    const int q   = l >> 4;
    const int sw  = row & 7;
    const int base_slot = row * 128;
    const bf16x8* Bb = (const bf16x8*)pack_b + (size_t)wv * 2048 + l;
    f32x4 acc = {0.f, 0.f, 0.f, 0.f};
    #pragma unroll 8
    for (int kb = 0; kb < 32; ++kb) {
        bf16x8 af = *(const bf16x8*)(Abf + 8 * (base_slot + ((kb * 4 + q) ^ sw)));
        bf16x8 bfr = Bb[(size_t)kb * 64];
        acc = __builtin_amdgcn_mfma_f32_16x16x32_bf16(af, bfr, acc, 0, 0, 0);
    }

    // ---- selection: out[b] = P[idx[b]][b]; coef for last-b of each row ----
    const int col = wv * 16 + (l & 15);
    #pragma unroll
    for (int j = 0; j < 4; ++j) {
        int r = q * 4 + j;                       // C-layout: col=l&15, row=(l>>4)*4+j
        u64 m = mask_lds[r];
        if ((m >> col) & 1) {
            float o = fminf(fmaxf(acc[j], LO_C), HI_C);
            out_logits[(size_t)col * (S_DIM + 1) + s + 1] = o;
            if (col == lastb_lds[r])
                coef_lds[r] = LR_C * (1.0f / (1.0f + expf(-o)) - target[col]);
        }
    }
    __syncthreads();

    // ---- update: independent RMW stream (W re-read is L2-hot from stage) ----
    float4*       D4 = (float4*)(new_weights + (size_t)s * (NWROWS * I_DIM));
    const float4* L4 = (const float4*)logit;
    #pragma unroll 8
    for (int r = 0; r < NWROWS; ++r) {
        const int lb = lastb_lds[r];
        float4 w = W4[r * 256 + t];
        float4 o;
        if (lb < 0) {
            o = w;
        } else {
            o = upd4(w, L4[lb * 256 + t], coef_lds[r]);
        }
        D4[r * 256 + t] = o;
    }
}

extern "C" void kernel_launch(void* const* d_in, const int* in_sizes, int n_in,
                              void* d_out, int out_size, void* d_ws, size_t ws_size,
                              hipStream_t stream) {
    const float* logit   = (const float*)d_in[0];   // [B, I, 1]
    const float* context = (const float*)d_in[1];   // [B, CTX]
    const float* target  = (const float*)d_in[2];   // [B, 1]
    const float* cm      = (const float*)d_in[3];   // [1, S, 4, CTX]
    const float* cb      = (const float*)d_in[4];   // [1, S, 4, 1]
    const float* weights = (const float*)d_in[5];   // [1, S, 16, I]
    const float* bias    = (const float*)d_in[6];   // [1]

    float* out_logits  = (float*)d_out;                       // [B, S+1]
    float* new_weights = out_logits + (size_t)B_DIM * (S_DIM + 1);

    char* ws = (char*)d_ws;
    float4* ctxT4  = (float4*)ws;    ws += (size_t)CTX4 * B_DIM * 16;   // 200704 B
    u64*    mask_g = (u64*)ws;       ws += (size_t)NTASK * 8;           // 130944 B
    short*  packb  = (short*)ws;                                        // 131072 B

    prep_kernel<<<CTX4 * B_DIM / 256, 256, 0, stream>>>(context, bias, ctxT4, out_logits);
    pack_kernel<<<32, 256, 0, stream>>>(logit, packb);
    gln_idx_kernel<<<S_DIM, 256, 0, stream>>>(cm, cb, ctxT4, mask_g);
    gln_mfma2_kernel<<<S_DIM, 256, 0, stream>>>(logit, target, weights, mask_g, packb,
                                                out_logits, new_weights);
}

// Round 12
// 58.809 us; speedup vs baseline: 1.3865x; 1.0864x over previous
//
#include <hip/hip_runtime.h>
#include <math.h>

typedef unsigned long long u64;
typedef __attribute__((ext_vector_type(8))) short bf16x8;
typedef __attribute__((ext_vector_type(4))) float f32x4;

#define S_DIM 1023
#define B_DIM 64
#define I_DIM 1024
#define CTX_DIM 784
#define CTX4 196          // CTX_DIM / 4
#define NWROWS 16         // 2^M buckets

#define LR_C 0.01f
#define WC_C 5.0f
#define LO_C (-6.906754778648554f)
#define HI_C ( 6.906754778648554f)

__device__ __forceinline__ float dot4(float4 a, float4 b) {
    return a.x * b.x + a.y * b.y + a.z * b.z + a.w * b.w;
}

__device__ __forceinline__ float4 upd4(float4 w, float4 a, float c) {
    float4 r;
    r.x = fminf(fmaxf(w.x - c * a.x, -WC_C), WC_C);
    r.y = fminf(fmaxf(w.y - c * a.y, -WC_C), WC_C);
    r.z = fminf(fmaxf(w.z - c * a.z, -WC_C), WC_C);
    r.w = fminf(fmaxf(w.w - c * a.w, -WC_C), WC_C);
    return r;
}

__device__ __forceinline__ short f2bf(float f) {
    union { float f; unsigned u; } cv; cv.f = f;
    unsigned r = cv.u + 0x7fffu + ((cv.u >> 16) & 1u);   // RNE
    return (short)(r >> 16);
}

// ---------------- kernel A: context -> float4-transposed layout + bias row ----------------
__global__ __launch_bounds__(256) void prep_kernel(
    const float* __restrict__ context,   // [B, CTX]
    const float* __restrict__ bias,      // [1]
    float4* __restrict__ ctxT4,          // [CTX4][B]
    float* __restrict__ out_logits)      // [B, S+1]
{
    int g = blockIdx.x * 256 + threadIdx.x;
    int k4 = g >> 6;
    int b  = g & 63;
    ctxT4[g] = *(const float4*)(context + (size_t)b * CTX_DIM + k4 * 4);
    if (g < B_DIM) out_logits[(size_t)g * (S_DIM + 1)] = bias[0];
}

// ---------------- kernel A2: pack logit into bf16 MFMA B-fragments ----------------
// pack_b[nt][kb][lane][j] = bf16(logit[b = nt*16+(l&15)][i = kb*32+(l>>4)*8+j])
__global__ __launch_bounds__(256) void pack_kernel(
    const float* __restrict__ logit,     // [B, I]
    short* __restrict__ pack_b)          // [4*32*64*8]
{
    int g = blockIdx.x * 256 + threadIdx.x;     // (nt*32+kb)*64 + l
    int l  = g & 63;
    int kb = (g >> 6) & 31;
    int nt = g >> 11;
    int b  = nt * 16 + (l & 15);
    int i0 = kb * 32 + (l >> 4) * 8;
    const float* src = logit + (size_t)b * I_DIM + i0;
    bf16x8 v;
    #pragma unroll
    for (int j = 0; j < 8; ++j) v[j] = f2bf(src[j]);
    *(bf16x8*)(pack_b + (size_t)g * 8) = v;
}

// ---------------- kernel C: fully fused -- idx + MFMA + reg-resident update ----------------
__global__ __launch_bounds__(256, 4) void gln_fused_kernel(
    const float* __restrict__ logit,     // [B, I] fp32
    const float* __restrict__ target,    // [B]
    const float* __restrict__ weights,   // [S, 16, I] fp32
    const float* __restrict__ cm,        // [S, 4, CTX]
    const float* __restrict__ cb,        // [S, 4]
    const float4* __restrict__ ctxT4,    // [CTX4][B]
    const short* __restrict__ pack_b,    // bf16 B-fragments
    float* __restrict__ out_logits,      // [B, S+1]
    float* __restrict__ new_weights)     // [S, 16, I]
{
    __shared__ short Abf[NWROWS * I_DIM];   // 32 KB swizzled bf16 W[s]
    __shared__ float red[4][4][64];         // [q][m][b]
    __shared__ int   bits[4][64];
    __shared__ float cb_lds[4];
    __shared__ u64   mask_lds[NWROWS];
    __shared__ int   lastb_lds[NWROWS];
    __shared__ float coef_lds[NWROWS];

    const int s  = blockIdx.x;
    const int t  = threadIdx.x;
    const int wv = t >> 6;
    const int l  = t & 63;

    // ---- issue W[s] -> 64 VGPRs immediately (HBM latency hides under idx phase) ----
    const float4* W4 = (const float4*)(weights + (size_t)s * (NWROWS * I_DIM));
    float4 Wr[16];
    #pragma unroll
    for (int j = 0; j < 16; ++j) Wr[j] = W4[t + j * 256];   // row j, cols 4t..4t+3

    if (t < 4) cb_lds[t] = cb[s * 4 + t];

    // ---- idx phase: halfspace hash (L2-bound, overlaps W HBM loads) ----
    {
        const int b = t & 63;
        const int q = __builtin_amdgcn_readfirstlane(t >> 6);
        const float4* cmr = (const float4*)(cm + (size_t)s * 4 * CTX_DIM);
        float a0 = 0.f, a1 = 0.f, a2 = 0.f, a3 = 0.f;
        const int k0 = q * 49;
        #pragma unroll 7
        for (int kk = 0; kk < 49; ++kk) {
            int k4 = k0 + kk;
            float4 c4 = ctxT4[k4 * 64 + b];
            a0 += dot4(cmr[k4], c4);
            a1 += dot4(cmr[CTX4 + k4], c4);
            a2 += dot4(cmr[2 * CTX4 + k4], c4);
            a3 += dot4(cmr[3 * CTX4 + k4], c4);
        }
        red[q][0][b] = a0;
        red[q][1][b] = a1;
        red[q][2][b] = a2;
        red[q][3][b] = a3;
    }
    __syncthreads();
    {
        int m = t >> 6, bb = t & 63;
        float sum = red[0][m][bb] + red[1][m][bb] + red[2][m][bb] + red[3][m][bb];
        bits[m][bb] = (sum > cb_lds[m]) ? 1 : 0;
    }
    __syncthreads();
    if (t < B_DIM) {   // wave 0: lane = b
        int v = bits[0][t] + 2 * bits[1][t] + 4 * bits[2][t] + 8 * bits[3][t];
        u64 my = 0;
        #pragma unroll
        for (int kk = 0; kk < NWROWS; ++kk) {
            u64 mk = __ballot(v == kk);
            if (t == kk) my = mk;
        }
        if (t < NWROWS) {
            mask_lds[t]  = my;
            lastb_lds[t] = my ? (63 - __clzll(my)) : -1;
        }
    }

    // ---- cvt W regs -> swizzled bf16 LDS (16B slot = row*128 + ((t>>1)^(row&7))) ----
    #pragma unroll
    for (int j = 0; j < 16; ++j) {
        int slot = j * 128 + ((t >> 1) ^ (j & 7));
        short4 v;
        v.x = f2bf(Wr[j].x); v.y = f2bf(Wr[j].y);
        v.z = f2bf(Wr[j].z); v.w = f2bf(Wr[j].w);
        *(short4*)(Abf + slot * 8 + (t & 1) * 4) = v;   // ds_write_b64
    }
    __syncthreads();

    // ---- MFMA: P[16][64] = W[s] . logit^T; wave wv -> cols wv*16..+15 ----
    const int row = l & 15;
    const int q2  = l >> 4;
    const int sw  = row & 7;
    const int base_slot = row * 128;
    const bf16x8* Bb = (const bf16x8*)pack_b + (size_t)wv * 2048 + l;
    f32x4 acc = {0.f, 0.f, 0.f, 0.f};
    #pragma unroll 8
    for (int kb = 0; kb < 32; ++kb) {
        bf16x8 af = *(const bf16x8*)(Abf + 8 * (base_slot + ((kb * 4 + q2) ^ sw)));
        bf16x8 bfr = Bb[(size_t)kb * 64];
        acc = __builtin_amdgcn_mfma_f32_16x16x32_bf16(af, bfr, acc, 0, 0, 0);
    }

    // ---- selection: out[b] = P[idx[b]][b]; coef for last-b of each row ----
    const int col = wv * 16 + (l & 15);
    #pragma unroll
    for (int j = 0; j < 4; ++j) {
        int r = q2 * 4 + j;                      // C-layout: col=l&15, row=(l>>4)*4+j
        u64 m = mask_lds[r];
        if ((m >> col) & 1) {
            float o = fminf(fmaxf(acc[j], LO_C), HI_C);
            out_logits[(size_t)col * (S_DIM + 1) + s + 1] = o;
            if (col == lastb_lds[r])
                coef_lds[r] = LR_C * (1.0f / (1.0f + expf(-o)) - target[col]);
        }
    }
    __syncthreads();

    // ---- update: stores straight from registers (no W re-read, fire-and-forget) ----
    float4*       D4 = (float4*)(new_weights + (size_t)s * (NWROWS * I_DIM));
    const float4* L4 = (const float4*)logit;
    #pragma unroll
    for (int r = 0; r < NWROWS; ++r) {
        const int lb = lastb_lds[r];
        float4 o;
        if (lb < 0) {
            o = Wr[r];
        } else {
            o = upd4(Wr[r], L4[lb * 256 + t], coef_lds[r]);
        }
        D4[r * 256 + t] = o;
    }
}

extern "C" void kernel_launch(void* const* d_in, const int* in_sizes, int n_in,
                              void* d_out, int out_size, void* d_ws, size_t ws_size,
                              hipStream_t stream) {
    const float* logit   = (const float*)d_in[0];   // [B, I, 1]
    const float* context = (const float*)d_in[1];   // [B, CTX]
    const float* target  = (const float*)d_in[2];   // [B, 1]
    const float* cm      = (const float*)d_in[3];   // [1, S, 4, CTX]
    const float* cb      = (const float*)d_in[4];   // [1, S, 4, 1]
    const float* weights = (const float*)d_in[5];   // [1, S, 16, I]
    const float* bias    = (const float*)d_in[6];   // [1]

    float* out_logits  = (float*)d_out;                       // [B, S+1]
    float* new_weights = out_logits + (size_t)B_DIM * (S_DIM + 1);

    char* ws = (char*)d_ws;
    float4* ctxT4 = (float4*)ws;     ws += (size_t)CTX4 * B_DIM * 16;   // 200704 B
    short*  packb = (short*)ws;                                         // 131072 B

    prep_kernel<<<CTX4 * B_DIM / 256, 256, 0, stream>>>(context, bias, ctxT4, out_logits);
    pack_kernel<<<32, 256, 0, stream>>>(logit, packb);
    gln_fused_kernel<<<S_DIM, 256, 0, stream>>>(logit, target, weights, cm, cb,
                                                ctxT4, packb, out_logits, new_weights);
}